// Round 27
// baseline (830.913 us; speedup 1.0000x reference)
//
#include <hip/hip_runtime.h>

#define N_NODES   10000
#define N_EDGES   50000
#define N_GRAPHS  64
#define NODE_DIM  32
#define EDGE_DIM  16
#define HID       64
#define EHID      128
#define T_STEPS   3
#define S2S_STEPS 6

typedef _Float16 half_t;
typedef _Float16 f16x8 __attribute__((ext_vector_type(8)));
typedef float    f32x4 __attribute__((ext_vector_type(4)));

__device__ __forceinline__ float sigf(float x){ return 1.0f/(1.0f + expf(-x)); }

__global__ void k_zero(float* p, int n){
  int i = blockIdx.x*256 + threadIdx.x;
  if (i < n) p[i] = 0.0f;
}

// h = nf @ W_proj + b_proj   (N x 64)
__global__ void k_proj(const float* __restrict__ nf, const float* __restrict__ Wp,
                       const float* __restrict__ bp, float* __restrict__ h){
  int idx = blockIdx.x*256 + threadIdx.x;
  if (idx >= N_NODES*HID) return;
  int n = idx >> 6;
  int c = idx & 63;
  float acc = bp[c];
  const float* row = nf + (size_t)n*NODE_DIM;
  for (int j = 0; j < NODE_DIM; ++j)
    acc = fmaf(row[j], Wp[j*HID + c], acc);
  h[idx] = acc;
}

// Mm (fp32, fallback path)
__global__ void k_tw2(const float* __restrict__ W2, float* __restrict__ Mm){
  int idx = blockIdx.x*256 + threadIdx.x;
  if (idx >= 64*8192) return;
  int j = idx >> 13; int o = idx & 8191; int k = o >> 6; int i = o & 63;
  Mm[idx] = W2[(size_t)k*4096 + i*64 + j];
}

// BT: W2 in MFMA B-fragment order (fp16), built once.
__global__ void k_w2bt(const float* __restrict__ W2, half_t* __restrict__ BT){
  int idx = blockIdx.x*256 + threadIdx.x;
  if (idx >= 512*2*64*8) return;
  int j    = idx & 7;
  int lane = (idx >> 3) & 63;
  int tk   = (idx >> 9) & 1;
  int tn   = idx >> 10;
  int k = tk*32 + ((lane >> 4) << 3) + j;
  int o = tn*16 + (lane & 15);
  BT[idx] = (half_t)W2[(size_t)(o >> 6)*4096 + (o & 63)*64 + k];
}

// AT: h in MFMA A-fragment order (fp16), per step.
__global__ void k_h2a(const float* __restrict__ h, half_t* __restrict__ AT){
  int idx = blockIdx.x*256 + threadIdx.x;
  if (idx >= 625*2*64*8) return;
  int j    = idx & 7;
  int lane = (idx >> 3) & 63;
  int tk   = (idx >> 9) & 1;
  int tm   = idx >> 10;
  int mrow = tm*16 + (lane & 15);
  int k    = tk*32 + ((lane >> 4) << 3) + j;
  AT[idx] = (half_t)h[(size_t)mrow*64 + k];
}

// GRU weight transposes
__global__ void k_twg(const float* __restrict__ Wg, const float* __restrict__ Wh,
                      float* __restrict__ WgT, float* __restrict__ WhT){
  int idx = blockIdx.x*256 + threadIdx.x;
  if (idx >= 192*64) return;
  int row = idx >> 6;
  int j   = idx & 63;
  WgT[j*192 + row] = Wg[(size_t)row*64 + j];
  WhT[j*192 + row] = Wh[(size_t)row*64 + j];
}

// LSTM weight transposes: WliT[j*256+row]=Wli[row*128+j]; WlhT[j*256+row]=Wlh[row*64+j]
__global__ void k_twl(const float* __restrict__ Wli, const float* __restrict__ Wlh,
                      float* __restrict__ WliT, float* __restrict__ WlhT){
  int idx = blockIdx.x*256 + threadIdx.x;
  if (idx < 256*128){
    int row = idx >> 7;
    int j   = idx & 127;
    WliT[j*256 + row] = Wli[(size_t)row*128 + j];
  } else if (idx < 256*128 + 256*64){
    int r   = idx - 256*128;
    int row = r >> 6;
    int j   = r & 63;
    WlhT[j*256 + row] = Wlh[(size_t)row*64 + j];
  }
}

// Hid = relu(ef @ W_e1 + b_e1)  (E x 128) — once per call
__global__ void k_ehid(const float* __restrict__ ef, const float* __restrict__ W1,
                       const float* __restrict__ b1, float* __restrict__ Hid){
  int idx = blockIdx.x*256 + threadIdx.x;
  if (idx >= N_EDGES*EHID) return;
  int e = idx >> 7, c = idx & 127;
  float acc = b1[c];
  const float* er = ef + (size_t)e*EDGE_DIM;
  for (int j = 0; j < EDGE_DIM; ++j)
    acc = fmaf(er[j], W1[j*EHID + c], acc);
  Hid[idx] = fmaxf(acc, 0.0f);
}

// bh[n,i] = sum_j be2[i*64+j] * h[n,j]
__global__ void k_bh(const float* __restrict__ h, const float* __restrict__ be2,
                     float* __restrict__ bh){
  int idx = blockIdx.x*256 + threadIdx.x;
  if (idx >= N_NODES*HID) return;
  int n = idx >> 6, i = idx & 63;
  float acc = 0.0f;
  const float* row = be2 + (size_t)i*64;
  const float* hr  = h + (size_t)n*64;
  for (int j = 0; j < 64; ++j)
    acc = fmaf(row[j], hr[j], acc);
  bh[idx] = acc;
}

// ---- CSR by src ----
__global__ void k_hist(const int* __restrict__ ei, int* __restrict__ deg){
  int e = blockIdx.x*256 + threadIdx.x;
  if (e >= N_EDGES) return;
  atomicAdd(&deg[ei[N_EDGES + e]], 1);
}

__global__ void k_scan(const int* __restrict__ deg, int* __restrict__ rowptr,
                       int* __restrict__ cursor){
  __shared__ int part[256];
  int t = threadIdx.x;
  int base = t*40;
  int s = 0;
  for (int i = 0; i < 40; ++i){
    int idx = base + i;
    if (idx < N_NODES) s += deg[idx];
  }
  part[t] = s;
  __syncthreads();
  for (int off = 1; off < 256; off <<= 1){
    int v = (t >= off) ? part[t - off] : 0;
    __syncthreads();
    part[t] += v;
    __syncthreads();
  }
  int run = (t > 0) ? part[t - 1] : 0;
  for (int i = 0; i < 40; ++i){
    int idx = base + i;
    if (idx < N_NODES){
      rowptr[idx] = run;
      cursor[idx] = run;
      run += deg[idx];
    }
  }
  if (t == 255) rowptr[N_NODES] = run;
}

__global__ void k_scatter(const int* __restrict__ ei, int* __restrict__ cursor,
                          int* __restrict__ csr){
  int e = blockIdx.x*256 + threadIdx.x;
  if (e >= N_EDGES) return;
  int src = ei[N_EDGES + e];
  int pos = atomicAdd(&cursor[src], 1);
  csr[pos] = e;
}

// MFMA C-GEMM (16x16x32_f16): wave = 16 rows x 64 cols, block = 4 waves
__global__ void k_cgemm_mfma(const half_t* __restrict__ AT,
                             const half_t* __restrict__ BT,
                             half_t* __restrict__ C){
  int wv   = threadIdx.x >> 6;
  int lane = threadIdx.x & 63;
  int tm = blockIdx.x*4 + wv;
  if (tm >= 625) return;
  const f16x8* Ab = (const f16x8*)AT + (size_t)tm*128;
  f16x8 a0 = Ab[lane];
  f16x8 a1 = Ab[64 + lane];
  int tn0 = blockIdx.y*4;
  f32x4 acc[4];
  #pragma unroll
  for (int s = 0; s < 4; ++s){ acc[s][0]=0.f; acc[s][1]=0.f; acc[s][2]=0.f; acc[s][3]=0.f; }
  #pragma unroll
  for (int s = 0; s < 4; ++s){
    const f16x8* Bb = (const f16x8*)BT + (size_t)(tn0 + s)*128;
    f16x8 b0 = Bb[lane];
    f16x8 b1 = Bb[64 + lane];
    acc[s] = __builtin_amdgcn_mfma_f32_16x16x32_f16(a0, b0, acc[s], 0, 0, 0);
    acc[s] = __builtin_amdgcn_mfma_f32_16x16x32_f16(a1, b1, acc[s], 0, 0, 0);
  }
  int quad = lane >> 4;
  int colb = lane & 15;
  int mbase = tm*16 + quad*4;
  #pragma unroll
  for (int s = 0; s < 4; ++s){
    size_t cb = (size_t)(tn0 + s)*16 + colb;
    #pragma unroll
    for (int r = 0; r < 4; ++r)
      C[(size_t)(mbase + r)*8192 + cb] = (half_t)acc[s][r];
  }
}

// scalar cgemm (fallback, chunked): 2 cols/thread, fp16 stores
__global__ void k_cgemm(const float* __restrict__ h, const float* __restrict__ Mm,
                        half_t* __restrict__ C, int lo, int hi){
  __shared__ float hs[16][64];
  int n0 = lo + blockIdx.x*16;
  int o0 = blockIdx.y*256 + threadIdx.x;
  for (int idx = threadIdx.x; idx < 16*64; idx += 256){
    int nn = idx >> 6, j = idx & 63;
    int node = n0 + nn;
    hs[nn][j] = (node < hi) ? h[(size_t)node*64 + j] : 0.0f;
  }
  __syncthreads();
  float acc0[16], acc1[16];
  #pragma unroll
  for (int nn = 0; nn < 16; ++nn){ acc0[nn] = 0.0f; acc1[nn] = 0.0f; }
  for (int j4 = 0; j4 < 16; ++j4){
    const float* M0 = Mm + (size_t)(j4*4)*8192;
    float a0 = M0[o0],            b0 = M0[o0 + 4096];
    float a1 = M0[8192 + o0],     b1 = M0[8192 + o0 + 4096];
    float a2 = M0[2*8192 + o0],   b2 = M0[2*8192 + o0 + 4096];
    float a3 = M0[3*8192 + o0],   b3 = M0[3*8192 + o0 + 4096];
    #pragma unroll
    for (int nn = 0; nn < 16; ++nn){
      float4 hv = *(const float4*)&hs[nn][j4*4];
      acc0[nn] = fmaf(hv.x, a0, acc0[nn]);
      acc1[nn] = fmaf(hv.x, b0, acc1[nn]);
      acc0[nn] = fmaf(hv.y, a1, acc0[nn]);
      acc1[nn] = fmaf(hv.y, b1, acc1[nn]);
      acc0[nn] = fmaf(hv.z, a2, acc0[nn]);
      acc1[nn] = fmaf(hv.z, b2, acc1[nn]);
      acc0[nn] = fmaf(hv.w, a3, acc0[nn]);
      acc1[nn] = fmaf(hv.w, b3, acc1[nn]);
    }
  }
  #pragma unroll
  for (int nn = 0; nn < 16; ++nn){
    int node = n0 + nn;
    if (node < hi){
      half_t* Cr = C + (size_t)(node - lo)*8192;
      Cr[o0]        = (half_t)acc0[nn];
      Cr[o0 + 4096] = (half_t)acc1[nn];
    }
  }
}

// One wave per SRC node: stream C[src] row once (fp16), apply to <=8 out-edges
__global__ void MPNN_55705725829535_kernel(const int* __restrict__ rowptr,
                                           const int* __restrict__ csr,
                                           const int* __restrict__ ei,
                                           const float* __restrict__ Hid,
                                           const half_t* __restrict__ C,
                                           const float* __restrict__ bh,
                                           float* __restrict__ m, int lo, int hi){
  __shared__ float hidL[4][8][128];
  int wave = threadIdx.x >> 6;
  int lane = threadIdx.x & 63;
  int s = lo + blockIdx.x*4 + wave;
  if (s >= hi) return;
  int beg = rowptr[s];
  int endp = rowptr[s + 1];
  if (beg == endp) return;
  float bhv = bh[(size_t)s*64 + lane];
  const half_t* Cb = C + (size_t)(s - lo)*8192 + lane;
  float (*hl)[128] = hidL[wave];
  for (int gbeg = beg; gbeg < endp; gbeg += 8){
    int gn = endp - gbeg; if (gn > 8) gn = 8;
    int dsts[8];
    int e0 = csr[gbeg];
    #pragma unroll
    for (int j = 0; j < 8; ++j){
      int e = (j < gn) ? csr[gbeg + j] : e0;
      dsts[j] = ei[e];
      hl[j][lane]      = Hid[(size_t)e*128 + lane];
      hl[j][lane + 64] = Hid[(size_t)e*128 + 64 + lane];
    }
    float acc[8];
    #pragma unroll
    for (int j = 0; j < 8; ++j) acc[j] = 0.0f;
    #pragma unroll 4
    for (int k = 0; k < 128; ++k){
      float c = (float)Cb[k*64];
      #pragma unroll
      for (int j = 0; j < 8; ++j)
        acc[j] = fmaf(hl[j][k], c, acc[j]);
    }
    for (int j = 0; j < gn; ++j)
      atomicAdd(&m[(size_t)dsts[j]*64 + lane], acc[j] + bhv);
  }
}

// fallback per-edge bilinear (only if ws too small for the C path)
__global__ void k_msg_fb(const int* __restrict__ ei, const float* __restrict__ ef,
                         const float* __restrict__ W1, const float* __restrict__ b1,
                         const float* __restrict__ W2, const float* __restrict__ be2,
                         const float* __restrict__ h, float* __restrict__ m){
  __shared__ float HidL[EHID];
  __shared__ __align__(16) float hsL[HID];
  int e = blockIdx.x;
  int t = threadIdx.x;
  int src = ei[N_EDGES + e];
  int dst = ei[e];
  {
    float a0 = b1[t];
    float a1 = b1[t + 64];
    const float* er = ef + (size_t)e*EDGE_DIM;
    for (int j = 0; j < EDGE_DIM; ++j){
      float ev = er[j];
      a0 = fmaf(ev, W1[j*EHID + t],      a0);
      a1 = fmaf(ev, W1[j*EHID + t + 64], a1);
    }
    HidL[t]      = fmaxf(a0, 0.0f);
    HidL[t + 64] = fmaxf(a1, 0.0f);
    hsL[t] = h[(size_t)src*64 + t];
  }
  __syncthreads();
  float acc = 0.0f;
  for (int k = 0; k < EHID; ++k){
    float s = HidL[k];
    if (s != 0.0f){
      const float* w = W2 + (size_t)k*4096 + t*64;
      float partial = 0.0f;
      for (int j = 0; j < 64; ++j)
        partial = fmaf(hsL[j], w[j], partial);
      acc = fmaf(s, partial, acc);
    }
  }
  {
    const float* w = be2 + (size_t)t*64;
    for (int j = 0; j < 64; ++j)
      acc = fmaf(hsL[j], w[j], acc);
  }
  atomicAdd(&m[(size_t)dst*64 + t], acc);
}

// GRU per node, transposed weights
__global__ void k_gru(float* __restrict__ h, const float* __restrict__ m,
                      const float* __restrict__ WgT, const float* __restrict__ WhT,
                      const float* __restrict__ bg, const float* __restrict__ bhb){
  __shared__ float mld[64];
  __shared__ float hld[64];
  int n = blockIdx.x;
  int i = threadIdx.x;
  mld[i] = m[(size_t)n*64 + i];
  hld[i] = h[(size_t)n*64 + i];
  __syncthreads();
  float xr = bg[i],  xz = bg[64 + i],  xn = bg[128 + i];
  float hr = bhb[i], hz = bhb[64 + i], hn = bhb[128 + i];
  for (int j = 0; j < 64; ++j){
    float mj = mld[j];
    float hj = hld[j];
    const float* wg = WgT + j*192;
    const float* wh = WhT + j*192;
    xr = fmaf(mj, wg[i],       xr);
    xz = fmaf(mj, wg[64 + i],  xz);
    xn = fmaf(mj, wg[128 + i], xn);
    hr = fmaf(hj, wh[i],       hr);
    hz = fmaf(hj, wh[64 + i],  hz);
    hn = fmaf(hj, wh[128 + i], hn);
  }
  float r  = sigf(xr + hr);
  float z  = sigf(xz + hz);
  float nn = tanhf(xn + r*hn);
  h[(size_t)n*64 + i] = (1.0f - z)*nn + z*hld[i];
}

// Set2Set + LSTM + readout; transposed LSTM weights (coalesced gates loop)
__global__ void k_s2s(const float* __restrict__ h,
                      const float* __restrict__ WliT, const float* __restrict__ WlhT,
                      const float* __restrict__ bli, const float* __restrict__ blh,
                      const float* __restrict__ Wm1, const float* __restrict__ bm1,
                      const float* __restrict__ Wm2, const float* __restrict__ bm2,
                      float* __restrict__ out){
  __shared__ float hc[157*65];
  __shared__ float ea[160];
  __shared__ float wred[4];
  __shared__ float gates[256];
  __shared__ float hsb[64];
  __shared__ float csb[64];
  __shared__ float rsb[64];
  int g = blockIdx.x;
  int t = threadIdx.x;
  int lane = t & 63;
  int wv   = t >> 6;
  int start = (g*N_NODES + 63) >> 6;
  int end   = ((g + 1)*N_NODES + 63) >> 6;
  int cnt = end - start;                      // 156 or 157
  const float* hg = h + (size_t)start*64;
  for (int idx = t; idx < cnt*64; idx += 256)
    hc[(idx >> 6)*65 + (idx & 63)] = hg[idx];
  if (t < 64){ hsb[t] = 0.0f; csb[t] = 0.0f; rsb[t] = 0.0f; }
  __syncthreads();
  for (int step = 0; step < S2S_STEPS; ++step){
    float ev = -1e30f;
    if (t < cnt){
      float a = 0.0f;
      const float* hr = &hc[t*65];
      for (int i = 0; i < 64; ++i) a = fmaf(hr[i], hsb[i], a);
      ev = a;
    }
    float v = ev;
    for (int o = 32; o > 0; o >>= 1) v = fmaxf(v, __shfl_xor(v, o));
    if (lane == 0) wred[wv] = v;
    __syncthreads();
    float mx = fmaxf(fmaxf(wred[0], wred[1]), fmaxf(wred[2], wred[3]));
    float ex = (t < cnt) ? expf(ev - mx) : 0.0f;
    float sv = ex;
    for (int o = 32; o > 0; o >>= 1) sv += __shfl_xor(sv, o);
    __syncthreads();
    if (lane == 0) wred[wv] = sv;
    __syncthreads();
    float ssum = wred[0] + wred[1] + wred[2] + wred[3];
    if (t < cnt) ea[t] = ex / (ssum + 1e-16f);
    __syncthreads();
    if (t < 64){
      float r = 0.0f;
      for (int n = 0; n < cnt; ++n) r = fmaf(ea[n], hc[n*65 + t], r);
      rsb[t] = r;
    }
    __syncthreads();
    {
      // coalesced: lane-consecutive reads of WliT/WlhT columns
      float gl = bli[t] + blh[t];
      for (int j = 0; j < 64; ++j) gl = fmaf(hsb[j], WliT[(size_t)j*256 + t],        gl);
      for (int j = 0; j < 64; ++j) gl = fmaf(rsb[j], WliT[(size_t)(64 + j)*256 + t], gl);
      for (int j = 0; j < 64; ++j) gl = fmaf(hsb[j], WlhT[(size_t)j*256 + t],        gl);
      gates[t] = gl;
    }
    __syncthreads();
    if (t < 64){
      float iv = sigf(gates[t]);
      float fv = sigf(gates[64 + t]);
      float gv = tanhf(gates[128 + t]);
      float ov = sigf(gates[192 + t]);
      float c  = fv*csb[t] + iv*gv;
      csb[t] = c;
      hsb[t] = ov*tanhf(c);
    }
    __syncthreads();
  }
  float rv = 0.0f;
  if (t < 64){
    float v = bm1[t];
    for (int j = 0; j < 64; ++j) v = fmaf(hsb[j], Wm1[(size_t)j*64 + t],        v);
    for (int j = 0; j < 64; ++j) v = fmaf(rsb[j], Wm1[(size_t)(64 + j)*64 + t], v);
    v = fmaxf(v, 0.0f);
    rv = v * Wm2[t];
  }
  for (int o = 32; o > 0; o >>= 1) rv += __shfl_xor(rv, o);
  if (lane == 0) wred[wv] = rv;
  __syncthreads();
  if (t == 0) out[g] = wred[0] + wred[1] + wred[2] + wred[3] + bm2[0];
}

extern "C" void kernel_launch(void* const* d_in, const int* in_sizes, int n_in,
                              void* d_out, int out_size, void* d_ws, size_t ws_size,
                              hipStream_t stream){
  (void)in_sizes; (void)n_in; (void)out_size;

  const float* nf  = (const float*)d_in[0];
  const float* ef  = (const float*)d_in[1];
  const int*   ei  = (const int*)d_in[2];
  const float* Wp  = (const float*)d_in[4];
  const float* bp  = (const float*)d_in[5];
  const float* We1 = (const float*)d_in[6];
  const float* be1 = (const float*)d_in[7];
  const float* We2 = (const float*)d_in[8];
  const float* be2 = (const float*)d_in[9];
  const float* Wg  = (const float*)d_in[10];
  const float* Wh  = (const float*)d_in[11];
  const float* bg  = (const float*)d_in[12];
  const float* bhb = (const float*)d_in[13];
  const float* Wli = (const float*)d_in[14];
  const float* Wlh = (const float*)d_in[15];
  const float* bli = (const float*)d_in[16];
  const float* blh = (const float*)d_in[17];
  const float* Wm1 = (const float*)d_in[18];
  const float* bm1 = (const float*)d_in[19];
  const float* Wm2 = (const float*)d_in[20];
  const float* bm2 = (const float*)d_in[21];

  float* out = (float*)d_out;
  float* ws  = (float*)d_ws;

  float* h     = ws;                        //   640000
  float* m     = ws + 640000;               //   640000
  float* bh    = ws + 1280000;              //   640000
  float* Mm    = ws + 1920000;              //   524288  (fallback)
  float* WgT   = ws + 2444288;              //    12288
  float* WhT   = ws + 2456576;              //    12288
  float* WliT  = ws + 2468864;              //    32768
  float* WlhT  = ws + 2501632;              //    16384
  float* Hid   = ws + 2518016;              //  6400000
  int*   deg    = (int*)(ws + 8918016);     //   10000
  int*   rowptr = deg + 10000;              //   10001
  int*   cursor = rowptr + 10001;           //   10000
  int*   csr    = cursor + 10000;           //   50000
  half_t* AT   = (half_t*)(ws + 8998032);   //  640000 halves
  half_t* BT   = (half_t*)(ws + 9318032);   //  524288 halves
  const size_t C_OFF = 9580176;             // floats
  half_t* C    = (half_t*)(ws + C_OFF);

  long long c_halves = ((long long)ws_size - (long long)C_OFF*4) / 2;
  int NC = (c_halves > 0) ? (int)(c_halves / 8192) : 0;
  if (NC > N_NODES) NC = N_NODES;
  int use_c_path = (NC >= 512);
  int use_mfma   = (NC >= N_NODES);

  k_proj<<<(N_NODES*HID + 255)/256, 256, 0, stream>>>(nf, Wp, bp, h);
  k_twl <<<(256*128 + 256*64 + 255)/256, 256, 0, stream>>>(Wli, Wlh, WliT, WlhT);

  if (use_c_path){
    k_twg <<<(192*64 + 255)/256, 256, 0, stream>>>(Wg, Wh, WgT, WhT);
    k_ehid<<<(N_EDGES*EHID + 255)/256, 256, 0, stream>>>(ef, We1, be1, Hid);
    k_zero<<<(10000 + 255)/256, 256, 0, stream>>>((float*)deg, 10000);
    k_hist<<<(N_EDGES + 255)/256, 256, 0, stream>>>(ei, deg);
    k_scan<<<1, 256, 0, stream>>>(deg, rowptr, cursor);
    k_scatter<<<(N_EDGES + 255)/256, 256, 0, stream>>>(ei, cursor, csr);
    if (use_mfma){
      k_w2bt<<<(512*2*64*8 + 255)/256, 256, 0, stream>>>(We2, BT);
      for (int step = 0; step < T_STEPS; ++step){
        k_zero<<<(N_NODES*HID + 255)/256, 256, 0, stream>>>(m, N_NODES*HID);
        k_bh<<<(N_NODES*HID + 255)/256, 256, 0, stream>>>(h, be2, bh);
        k_h2a<<<(625*2*64*8 + 255)/256, 256, 0, stream>>>(h, AT);
        dim3 grid(157, 128);
        k_cgemm_mfma<<<grid, 256, 0, stream>>>(AT, BT, C);
        MPNN_55705725829535_kernel<<<(N_NODES + 3)/4, 256, 0, stream>>>(
            rowptr, csr, ei, Hid, C, bh, m, 0, N_NODES);
        k_gru<<<N_NODES, 64, 0, stream>>>(h, m, WgT, WhT, bg, bhb);
      }
    } else {
      k_tw2<<<(64*8192)/256, 256, 0, stream>>>(We2, Mm);
      for (int step = 0; step < T_STEPS; ++step){
        k_zero<<<(N_NODES*HID + 255)/256, 256, 0, stream>>>(m, N_NODES*HID);
        k_bh<<<(N_NODES*HID + 255)/256, 256, 0, stream>>>(h, be2, bh);
        for (int lo = 0; lo < N_NODES; lo += NC){
          int hi = (lo + NC < N_NODES) ? lo + NC : N_NODES;
          int cnt = hi - lo;
          dim3 grid((cnt + 15)/16, 16);
          k_cgemm<<<grid, 256, 0, stream>>>(h, Mm, C, lo, hi);
          MPNN_55705725829535_kernel<<<(cnt + 3)/4, 256, 0, stream>>>(
              rowptr, csr, ei, Hid, C, bh, m, lo, hi);
        }
        k_gru<<<N_NODES, 64, 0, stream>>>(h, m, WgT, WhT, bg, bhb);
      }
    }
  } else {
    k_twg <<<(192*64 + 255)/256, 256, 0, stream>>>(Wg, Wh, WgT, WhT);
    for (int step = 0; step < T_STEPS; ++step){
      k_zero<<<(N_NODES*HID + 255)/256, 256, 0, stream>>>(m, N_NODES*HID);
      k_msg_fb<<<N_EDGES, 64, 0, stream>>>(ei, ef, We1, be1, We2, be2, h, m);
      k_gru<<<N_NODES, 64, 0, stream>>>(h, m, WgT, WhT, bg, bhb);
    }
  }
  k_s2s<<<N_GRAPHS, 256, 0, stream>>>(h, WliT, WlhT, bli, blh,
                                      Wm1, bm1, Wm2, bm2, out);
}

// Round 28
// 700.726 us; speedup vs baseline: 1.1858x; 1.1858x over previous
//
#include <hip/hip_runtime.h>

#define N_NODES   10000
#define N_EDGES   50000
#define N_GRAPHS  64
#define NODE_DIM  32
#define EDGE_DIM  16
#define HID       64
#define EHID      128
#define T_STEPS   3
#define S2S_STEPS 6

typedef _Float16 half_t;
typedef _Float16 f16x8 __attribute__((ext_vector_type(8)));
typedef float    f32x4 __attribute__((ext_vector_type(4)));

__device__ __forceinline__ float sigf(float x){ return 1.0f/(1.0f + expf(-x)); }

__global__ void k_zero(float* p, int n){
  int i = blockIdx.x*256 + threadIdx.x;
  if (i < n) p[i] = 0.0f;
}

// h = nf @ W_proj + b_proj   (N x 64)
__global__ void k_proj(const float* __restrict__ nf, const float* __restrict__ Wp,
                       const float* __restrict__ bp, float* __restrict__ h){
  int idx = blockIdx.x*256 + threadIdx.x;
  if (idx >= N_NODES*HID) return;
  int n = idx >> 6;
  int c = idx & 63;
  float acc = bp[c];
  const float* row = nf + (size_t)n*NODE_DIM;
  for (int j = 0; j < NODE_DIM; ++j)
    acc = fmaf(row[j], Wp[j*HID + c], acc);
  h[idx] = acc;
}

// Mm (fp32, fallback path)
__global__ void k_tw2(const float* __restrict__ W2, float* __restrict__ Mm){
  int idx = blockIdx.x*256 + threadIdx.x;
  if (idx >= 64*8192) return;
  int j = idx >> 13; int o = idx & 8191; int k = o >> 6; int i = o & 63;
  Mm[idx] = W2[(size_t)k*4096 + i*64 + j];
}

// BT: W2 in MFMA B-fragment order (fp16), built once.
__global__ void k_w2bt(const float* __restrict__ W2, half_t* __restrict__ BT){
  int idx = blockIdx.x*256 + threadIdx.x;
  if (idx >= 512*2*64*8) return;
  int j    = idx & 7;
  int lane = (idx >> 3) & 63;
  int tk   = (idx >> 9) & 1;
  int tn   = idx >> 10;
  int k = tk*32 + ((lane >> 4) << 3) + j;
  int o = tn*16 + (lane & 15);
  BT[idx] = (half_t)W2[(size_t)(o >> 6)*4096 + (o & 63)*64 + k];
}

// AT: h in MFMA A-fragment order (fp16), per step.
__global__ void k_h2a(const float* __restrict__ h, half_t* __restrict__ AT){
  int idx = blockIdx.x*256 + threadIdx.x;
  if (idx >= 625*2*64*8) return;
  int j    = idx & 7;
  int lane = (idx >> 3) & 63;
  int tk   = (idx >> 9) & 1;
  int tm   = idx >> 10;
  int mrow = tm*16 + (lane & 15);
  int k    = tk*32 + ((lane >> 4) << 3) + j;
  AT[idx] = (half_t)h[(size_t)mrow*64 + k];
}

// GRU weight transposes
__global__ void k_twg(const float* __restrict__ Wg, const float* __restrict__ Wh,
                      float* __restrict__ WgT, float* __restrict__ WhT){
  int idx = blockIdx.x*256 + threadIdx.x;
  if (idx >= 192*64) return;
  int row = idx >> 6;
  int j   = idx & 63;
  WgT[j*192 + row] = Wg[(size_t)row*64 + j];
  WhT[j*192 + row] = Wh[(size_t)row*64 + j];
}

// Hid = relu(ef @ W_e1 + b_e1)  (E x 128) — once per call
__global__ void k_ehid(const float* __restrict__ ef, const float* __restrict__ W1,
                       const float* __restrict__ b1, float* __restrict__ Hid){
  int idx = blockIdx.x*256 + threadIdx.x;
  if (idx >= N_EDGES*EHID) return;
  int e = idx >> 7, c = idx & 127;
  float acc = b1[c];
  const float* er = ef + (size_t)e*EDGE_DIM;
  for (int j = 0; j < EDGE_DIM; ++j)
    acc = fmaf(er[j], W1[j*EHID + c], acc);
  Hid[idx] = fmaxf(acc, 0.0f);
}

// bh[n,i] = sum_j be2[i*64+j] * h[n,j]
__global__ void k_bh(const float* __restrict__ h, const float* __restrict__ be2,
                     float* __restrict__ bh){
  int idx = blockIdx.x*256 + threadIdx.x;
  if (idx >= N_NODES*HID) return;
  int n = idx >> 6, i = idx & 63;
  float acc = 0.0f;
  const float* row = be2 + (size_t)i*64;
  const float* hr  = h + (size_t)n*64;
  for (int j = 0; j < 64; ++j)
    acc = fmaf(row[j], hr[j], acc);
  bh[idx] = acc;
}

// ---- CSR by src ----
__global__ void k_hist(const int* __restrict__ ei, int* __restrict__ deg){
  int e = blockIdx.x*256 + threadIdx.x;
  if (e >= N_EDGES) return;
  atomicAdd(&deg[ei[N_EDGES + e]], 1);
}

__global__ void k_scan(const int* __restrict__ deg, int* __restrict__ rowptr,
                       int* __restrict__ cursor){
  __shared__ int part[256];
  int t = threadIdx.x;
  int base = t*40;
  int s = 0;
  for (int i = 0; i < 40; ++i){
    int idx = base + i;
    if (idx < N_NODES) s += deg[idx];
  }
  part[t] = s;
  __syncthreads();
  for (int off = 1; off < 256; off <<= 1){
    int v = (t >= off) ? part[t - off] : 0;
    __syncthreads();
    part[t] += v;
    __syncthreads();
  }
  int run = (t > 0) ? part[t - 1] : 0;
  for (int i = 0; i < 40; ++i){
    int idx = base + i;
    if (idx < N_NODES){
      rowptr[idx] = run;
      cursor[idx] = run;
      run += deg[idx];
    }
  }
  if (t == 255) rowptr[N_NODES] = run;
}

__global__ void k_scatter(const int* __restrict__ ei, int* __restrict__ cursor,
                          int* __restrict__ csr){
  int e = blockIdx.x*256 + threadIdx.x;
  if (e >= N_EDGES) return;
  int src = ei[N_EDGES + e];
  int pos = atomicAdd(&cursor[src], 1);
  csr[pos] = e;
}

// MFMA C-GEMM (16x16x32_f16): wave = 16 rows x 64 cols, block = 4 waves
__global__ void k_cgemm_mfma(const half_t* __restrict__ AT,
                             const half_t* __restrict__ BT,
                             half_t* __restrict__ C){
  int wv   = threadIdx.x >> 6;
  int lane = threadIdx.x & 63;
  int tm = blockIdx.x*4 + wv;
  if (tm >= 625) return;
  const f16x8* Ab = (const f16x8*)AT + (size_t)tm*128;
  f16x8 a0 = Ab[lane];
  f16x8 a1 = Ab[64 + lane];
  int tn0 = blockIdx.y*4;
  f32x4 acc[4];
  #pragma unroll
  for (int s = 0; s < 4; ++s){ acc[s][0]=0.f; acc[s][1]=0.f; acc[s][2]=0.f; acc[s][3]=0.f; }
  #pragma unroll
  for (int s = 0; s < 4; ++s){
    const f16x8* Bb = (const f16x8*)BT + (size_t)(tn0 + s)*128;
    f16x8 b0 = Bb[lane];
    f16x8 b1 = Bb[64 + lane];
    acc[s] = __builtin_amdgcn_mfma_f32_16x16x32_f16(a0, b0, acc[s], 0, 0, 0);
    acc[s] = __builtin_amdgcn_mfma_f32_16x16x32_f16(a1, b1, acc[s], 0, 0, 0);
  }
  int quad = lane >> 4;
  int colb = lane & 15;
  int mbase = tm*16 + quad*4;
  #pragma unroll
  for (int s = 0; s < 4; ++s){
    size_t cb = (size_t)(tn0 + s)*16 + colb;
    #pragma unroll
    for (int r = 0; r < 4; ++r)
      C[(size_t)(mbase + r)*8192 + cb] = (half_t)acc[s][r];
  }
}

// scalar cgemm (fallback, chunked): 2 cols/thread, fp16 stores
__global__ void k_cgemm(const float* __restrict__ h, const float* __restrict__ Mm,
                        half_t* __restrict__ C, int lo, int hi){
  __shared__ float hs[16][64];
  int n0 = lo + blockIdx.x*16;
  int o0 = blockIdx.y*256 + threadIdx.x;
  for (int idx = threadIdx.x; idx < 16*64; idx += 256){
    int nn = idx >> 6, j = idx & 63;
    int node = n0 + nn;
    hs[nn][j] = (node < hi) ? h[(size_t)node*64 + j] : 0.0f;
  }
  __syncthreads();
  float acc0[16], acc1[16];
  #pragma unroll
  for (int nn = 0; nn < 16; ++nn){ acc0[nn] = 0.0f; acc1[nn] = 0.0f; }
  for (int j4 = 0; j4 < 16; ++j4){
    const float* M0 = Mm + (size_t)(j4*4)*8192;
    float a0 = M0[o0],            b0 = M0[o0 + 4096];
    float a1 = M0[8192 + o0],     b1 = M0[8192 + o0 + 4096];
    float a2 = M0[2*8192 + o0],   b2 = M0[2*8192 + o0 + 4096];
    float a3 = M0[3*8192 + o0],   b3 = M0[3*8192 + o0 + 4096];
    #pragma unroll
    for (int nn = 0; nn < 16; ++nn){
      float4 hv = *(const float4*)&hs[nn][j4*4];
      acc0[nn] = fmaf(hv.x, a0, acc0[nn]);
      acc1[nn] = fmaf(hv.x, b0, acc1[nn]);
      acc0[nn] = fmaf(hv.y, a1, acc0[nn]);
      acc1[nn] = fmaf(hv.y, b1, acc1[nn]);
      acc0[nn] = fmaf(hv.z, a2, acc0[nn]);
      acc1[nn] = fmaf(hv.z, b2, acc1[nn]);
      acc0[nn] = fmaf(hv.w, a3, acc0[nn]);
      acc1[nn] = fmaf(hv.w, b3, acc1[nn]);
    }
  }
  #pragma unroll
  for (int nn = 0; nn < 16; ++nn){
    int node = n0 + nn;
    if (node < hi){
      half_t* Cr = C + (size_t)(node - lo)*8192;
      Cr[o0]        = (half_t)acc0[nn];
      Cr[o0 + 4096] = (half_t)acc1[nn];
    }
  }
}

// One wave per SRC node: stream C[src] row once (fp16), apply to <=8 out-edges
__global__ void MPNN_55705725829535_kernel(const int* __restrict__ rowptr,
                                           const int* __restrict__ csr,
                                           const int* __restrict__ ei,
                                           const float* __restrict__ Hid,
                                           const half_t* __restrict__ C,
                                           const float* __restrict__ bh,
                                           float* __restrict__ m, int lo, int hi){
  __shared__ float hidL[4][8][128];
  int wave = threadIdx.x >> 6;
  int lane = threadIdx.x & 63;
  int s = lo + blockIdx.x*4 + wave;
  if (s >= hi) return;
  int beg = rowptr[s];
  int endp = rowptr[s + 1];
  if (beg == endp) return;
  float bhv = bh[(size_t)s*64 + lane];
  const half_t* Cb = C + (size_t)(s - lo)*8192 + lane;
  float (*hl)[128] = hidL[wave];
  for (int gbeg = beg; gbeg < endp; gbeg += 8){
    int gn = endp - gbeg; if (gn > 8) gn = 8;
    int dsts[8];
    int e0 = csr[gbeg];
    #pragma unroll
    for (int j = 0; j < 8; ++j){
      int e = (j < gn) ? csr[gbeg + j] : e0;
      dsts[j] = ei[e];
      hl[j][lane]      = Hid[(size_t)e*128 + lane];
      hl[j][lane + 64] = Hid[(size_t)e*128 + 64 + lane];
    }
    float acc[8];
    #pragma unroll
    for (int j = 0; j < 8; ++j) acc[j] = 0.0f;
    #pragma unroll 4
    for (int k = 0; k < 128; ++k){
      float c = (float)Cb[k*64];
      #pragma unroll
      for (int j = 0; j < 8; ++j)
        acc[j] = fmaf(hl[j][k], c, acc[j]);
    }
    for (int j = 0; j < gn; ++j)
      atomicAdd(&m[(size_t)dsts[j]*64 + lane], acc[j] + bhv);
  }
}

// fallback per-edge bilinear (only if ws too small for the C path)
__global__ void k_msg_fb(const int* __restrict__ ei, const float* __restrict__ ef,
                         const float* __restrict__ W1, const float* __restrict__ b1,
                         const float* __restrict__ W2, const float* __restrict__ be2,
                         const float* __restrict__ h, float* __restrict__ m){
  __shared__ float HidL[EHID];
  __shared__ __align__(16) float hsL[HID];
  int e = blockIdx.x;
  int t = threadIdx.x;
  int src = ei[N_EDGES + e];
  int dst = ei[e];
  {
    float a0 = b1[t];
    float a1 = b1[t + 64];
    const float* er = ef + (size_t)e*EDGE_DIM;
    for (int j = 0; j < EDGE_DIM; ++j){
      float ev = er[j];
      a0 = fmaf(ev, W1[j*EHID + t],      a0);
      a1 = fmaf(ev, W1[j*EHID + t + 64], a1);
    }
    HidL[t]      = fmaxf(a0, 0.0f);
    HidL[t + 64] = fmaxf(a1, 0.0f);
    hsL[t] = h[(size_t)src*64 + t];
  }
  __syncthreads();
  float acc = 0.0f;
  for (int k = 0; k < EHID; ++k){
    float s = HidL[k];
    if (s != 0.0f){
      const float* w = W2 + (size_t)k*4096 + t*64;
      float partial = 0.0f;
      for (int j = 0; j < 64; ++j)
        partial = fmaf(hsL[j], w[j], partial);
      acc = fmaf(s, partial, acc);
    }
  }
  {
    const float* w = be2 + (size_t)t*64;
    for (int j = 0; j < 64; ++j)
      acc = fmaf(hsL[j], w[j], acc);
  }
  atomicAdd(&m[(size_t)dst*64 + t], acc);
}

// GRU per node, transposed weights
__global__ void k_gru(float* __restrict__ h, const float* __restrict__ m,
                      const float* __restrict__ WgT, const float* __restrict__ WhT,
                      const float* __restrict__ bg, const float* __restrict__ bhb){
  __shared__ float mld[64];
  __shared__ float hld[64];
  int n = blockIdx.x;
  int i = threadIdx.x;
  mld[i] = m[(size_t)n*64 + i];
  hld[i] = h[(size_t)n*64 + i];
  __syncthreads();
  float xr = bg[i],  xz = bg[64 + i],  xn = bg[128 + i];
  float hr = bhb[i], hz = bhb[64 + i], hn = bhb[128 + i];
  for (int j = 0; j < 64; ++j){
    float mj = mld[j];
    float hj = hld[j];
    const float* wg = WgT + j*192;
    const float* wh = WhT + j*192;
    xr = fmaf(mj, wg[i],       xr);
    xz = fmaf(mj, wg[64 + i],  xz);
    xn = fmaf(mj, wg[128 + i], xn);
    hr = fmaf(hj, wh[i],       hr);
    hz = fmaf(hj, wh[64 + i],  hz);
    hn = fmaf(hj, wh[128 + i], hn);
  }
  float r  = sigf(xr + hr);
  float z  = sigf(xz + hz);
  float nn = tanhf(xn + r*hn);
  h[(size_t)n*64 + i] = (1.0f - z)*nn + z*hld[i];
}

// Set2Set + LSTM + readout; 512 threads: rsb 8-way split, gates 2-way split.
// Direct Wli/Wlh reads (L1-resident per-thread rows — proven faster than
// transposed at 1-block/CU occupancy, r26 vs r27).
__global__ void k_s2s(const float* __restrict__ h,
                      const float* __restrict__ Wli, const float* __restrict__ Wlh,
                      const float* __restrict__ bli, const float* __restrict__ blh,
                      const float* __restrict__ Wm1, const float* __restrict__ bm1,
                      const float* __restrict__ Wm2, const float* __restrict__ bm2,
                      float* __restrict__ out){
  __shared__ float hc[157*65];
  __shared__ float ea[160];
  __shared__ float x[192];
  __shared__ float gpart[512];
  __shared__ float rsp[8][64];
  __shared__ float wredA[8];
  __shared__ float wredB[8];
  __shared__ float hsb[64];
  __shared__ float csb[64];
  __shared__ float rsb[64];
  int g = blockIdx.x;
  int t = threadIdx.x;          // 0..511
  int lane = t & 63;
  int wv   = t >> 6;            // 0..7
  int start = (g*N_NODES + 63) >> 6;
  int end   = ((g + 1)*N_NODES + 63) >> 6;
  int cnt = end - start;        // 156 or 157
  const float* hg = h + (size_t)start*64;
  for (int idx = t; idx < cnt*64; idx += 512)
    hc[(idx >> 6)*65 + (idx & 63)] = hg[idx];
  if (t < 64){ hsb[t] = 0.0f; csb[t] = 0.0f; rsb[t] = 0.0f; }
  __syncthreads();
  for (int step = 0; step < S2S_STEPS; ++step){
    float ev = -1e30f;
    if (t < cnt){
      float a = 0.0f;
      const float* hr = &hc[t*65];
      for (int i = 0; i < 64; ++i) a = fmaf(hr[i], hsb[i], a);
      ev = a;
    }
    float v = ev;
    for (int o = 32; o > 0; o >>= 1) v = fmaxf(v, __shfl_xor(v, o));
    if (lane == 0) wredA[wv] = v;
    __syncthreads();                                      // S1
    float mx = wredA[0];
    #pragma unroll
    for (int i = 1; i < 8; ++i) mx = fmaxf(mx, wredA[i]);
    float ex = (t < cnt) ? expf(ev - mx) : 0.0f;
    float sv = ex;
    for (int o = 32; o > 0; o >>= 1) sv += __shfl_xor(sv, o);
    if (lane == 0) wredB[wv] = sv;
    __syncthreads();                                      // S2
    float ssum = 0.0f;
    #pragma unroll
    for (int i = 0; i < 8; ++i) ssum += wredB[i];
    if (t < cnt) ea[t] = ex / (ssum + 1e-16f);
    __syncthreads();                                      // S3
    {
      int n0 = wv*20;
      int n1 = n0 + 20; if (n1 > cnt) n1 = cnt;
      float r = 0.0f;
      for (int n = n0; n < n1; ++n)
        r = fmaf(ea[n], hc[n*65 + lane], r);
      rsp[wv][lane] = r;
    }
    __syncthreads();                                      // S4
    if (t < 64){
      float r = rsp[0][t] + rsp[1][t] + rsp[2][t] + rsp[3][t]
              + rsp[4][t] + rsp[5][t] + rsp[6][t] + rsp[7][t];
      rsb[t] = r;
      x[t]        = hsb[t];
      x[64 + t]   = r;
      x[128 + t]  = hsb[t];
    }
    __syncthreads();                                      // S5
    {
      int gate = t & 255;
      int half = t >> 8;
      float gl = 0.0f;
      if (half == 0){
        const float* wr = Wli + (size_t)gate*128;
        for (int jj = 0; jj < 96; ++jj) gl = fmaf(x[jj], wr[jj], gl);
      } else {
        const float* wr = Wli + (size_t)gate*128;
        for (int jj = 96; jj < 128; ++jj) gl = fmaf(x[jj], wr[jj], gl);
        const float* wh = Wlh + (size_t)gate*64;
        for (int jj = 0; jj < 64; ++jj) gl = fmaf(x[128 + jj], wh[jj], gl);
      }
      gpart[t] = gl;
    }
    __syncthreads();                                      // S6
    if (t < 64){
      float iv = sigf (gpart[t]       + gpart[t + 256]       + bli[t]       + blh[t]);
      float fv = sigf (gpart[64 + t]  + gpart[64 + t + 256]  + bli[64 + t]  + blh[64 + t]);
      float gv = tanhf(gpart[128 + t] + gpart[128 + t + 256] + bli[128 + t] + blh[128 + t]);
      float ov = sigf (gpart[192 + t] + gpart[192 + t + 256] + bli[192 + t] + blh[192 + t]);
      float c  = fv*csb[t] + iv*gv;
      csb[t] = c;
      hsb[t] = ov*tanhf(c);
    }
    __syncthreads();                                      // S7
  }
  float rv = 0.0f;
  if (t < 64){
    float v = bm1[t];
    for (int j = 0; j < 64; ++j) v = fmaf(hsb[j], Wm1[(size_t)j*64 + t],        v);
    for (int j = 0; j < 64; ++j) v = fmaf(rsb[j], Wm1[(size_t)(64 + j)*64 + t], v);
    v = fmaxf(v, 0.0f);
    rv = v * Wm2[t];
  }
  for (int o = 32; o > 0; o >>= 1) rv += __shfl_xor(rv, o);
  if (lane == 0) wredA[wv] = rv;
  __syncthreads();
  if (t == 0) out[g] = wredA[0] + wredA[1] + wredA[2] + wredA[3]
                     + wredA[4] + wredA[5] + wredA[6] + wredA[7] + bm2[0];
}

extern "C" void kernel_launch(void* const* d_in, const int* in_sizes, int n_in,
                              void* d_out, int out_size, void* d_ws, size_t ws_size,
                              hipStream_t stream){
  (void)in_sizes; (void)n_in; (void)out_size;

  const float* nf  = (const float*)d_in[0];
  const float* ef  = (const float*)d_in[1];
  const int*   ei  = (const int*)d_in[2];
  const float* Wp  = (const float*)d_in[4];
  const float* bp  = (const float*)d_in[5];
  const float* We1 = (const float*)d_in[6];
  const float* be1 = (const float*)d_in[7];
  const float* We2 = (const float*)d_in[8];
  const float* be2 = (const float*)d_in[9];
  const float* Wg  = (const float*)d_in[10];
  const float* Wh  = (const float*)d_in[11];
  const float* bg  = (const float*)d_in[12];
  const float* bhb = (const float*)d_in[13];
  const float* Wli = (const float*)d_in[14];
  const float* Wlh = (const float*)d_in[15];
  const float* bli = (const float*)d_in[16];
  const float* blh = (const float*)d_in[17];
  const float* Wm1 = (const float*)d_in[18];
  const float* bm1 = (const float*)d_in[19];
  const float* Wm2 = (const float*)d_in[20];
  const float* bm2 = (const float*)d_in[21];

  float* out = (float*)d_out;
  float* ws  = (float*)d_ws;

  float* h    = ws;                         //   640000
  float* m    = ws + 640000;                //   640000
  float* bh   = ws + 1280000;               //   640000
  float* Mm   = ws + 1920000;               //   524288  (fallback)
  float* WgT  = ws + 2444288;               //    12288
  float* WhT  = ws + 2456576;               //    12288
  float* Hid  = ws + 2468864;               //  6400000
  int*   deg    = (int*)(ws + 8868864);
  int*   rowptr = deg + 10000;
  int*   cursor = rowptr + 10001;
  int*   csr    = cursor + 10000;
  half_t* AT  = (half_t*)(ws + 8948880);
  half_t* BT  = (half_t*)(ws + 9268880);
  const size_t C_OFF = 9531024;             // floats
  half_t* C   = (half_t*)(ws + C_OFF);

  long long c_halves = ((long long)ws_size - (long long)C_OFF*4) / 2;
  int NC = (c_halves > 0) ? (int)(c_halves / 8192) : 0;
  if (NC > N_NODES) NC = N_NODES;
  int use_c_path = (NC >= 512);
  int use_mfma   = (NC >= N_NODES);

  k_proj<<<(N_NODES*HID + 255)/256, 256, 0, stream>>>(nf, Wp, bp, h);

  if (use_c_path){
    k_twg <<<(192*64 + 255)/256, 256, 0, stream>>>(Wg, Wh, WgT, WhT);
    k_ehid<<<(N_EDGES*EHID + 255)/256, 256, 0, stream>>>(ef, We1, be1, Hid);
    k_zero<<<(10000 + 255)/256, 256, 0, stream>>>((float*)deg, 10000);
    k_hist<<<(N_EDGES + 255)/256, 256, 0, stream>>>(ei, deg);
    k_scan<<<1, 256, 0, stream>>>(deg, rowptr, cursor);
    k_scatter<<<(N_EDGES + 255)/256, 256, 0, stream>>>(ei, cursor, csr);
    if (use_mfma){
      k_w2bt<<<(512*2*64*8 + 255)/256, 256, 0, stream>>>(We2, BT);
      for (int step = 0; step < T_STEPS; ++step){
        k_zero<<<(N_NODES*HID + 255)/256, 256, 0, stream>>>(m, N_NODES*HID);
        k_bh<<<(N_NODES*HID + 255)/256, 256, 0, stream>>>(h, be2, bh);
        k_h2a<<<(625*2*64*8 + 255)/256, 256, 0, stream>>>(h, AT);
        dim3 grid(157, 128);
        k_cgemm_mfma<<<grid, 256, 0, stream>>>(AT, BT, C);
        MPNN_55705725829535_kernel<<<(N_NODES + 3)/4, 256, 0, stream>>>(
            rowptr, csr, ei, Hid, C, bh, m, 0, N_NODES);
        k_gru<<<N_NODES, 64, 0, stream>>>(h, m, WgT, WhT, bg, bhb);
      }
    } else {
      k_tw2<<<(64*8192)/256, 256, 0, stream>>>(We2, Mm);
      for (int step = 0; step < T_STEPS; ++step){
        k_zero<<<(N_NODES*HID + 255)/256, 256, 0, stream>>>(m, N_NODES*HID);
        k_bh<<<(N_NODES*HID + 255)/256, 256, 0, stream>>>(h, be2, bh);
        for (int lo = 0; lo < N_NODES; lo += NC){
          int hi = (lo + NC < N_NODES) ? lo + NC : N_NODES;
          int cnt = hi - lo;
          dim3 grid((cnt + 15)/16, 16);
          k_cgemm<<<grid, 256, 0, stream>>>(h, Mm, C, lo, hi);
          MPNN_55705725829535_kernel<<<(cnt + 3)/4, 256, 0, stream>>>(
              rowptr, csr, ei, Hid, C, bh, m, lo, hi);
        }
        k_gru<<<N_NODES, 64, 0, stream>>>(h, m, WgT, WhT, bg, bhb);
      }
    }
  } else {
    k_twg <<<(192*64 + 255)/256, 256, 0, stream>>>(Wg, Wh, WgT, WhT);
    for (int step = 0; step < T_STEPS; ++step){
      k_zero<<<(N_NODES*HID + 255)/256, 256, 0, stream>>>(m, N_NODES*HID);
      k_msg_fb<<<N_EDGES, 64, 0, stream>>>(ei, ef, We1, be1, We2, be2, h, m);
      k_gru<<<N_NODES, 64, 0, stream>>>(h, m, WgT, WhT, bg, bhb);
    }
  }
  k_s2s<<<N_GRAPHS, 512, 0, stream>>>(h, Wli, Wlh, bli, blh,
                                      Wm1, bm1, Wm2, bm2, out);
}